// Round 2
// baseline (434.563 us; speedup 1.0000x reference)
//
#include <hip/hip_runtime.h>

// Model constants (fixed by the reference)
constexpr int N_   = 512;
constexpr int D_   = 64;
constexpr int H_   = 6;
constexpr int DH_  = 32;
constexpr int CB_  = 16;
constexpr int SB_  = 8;
constexpr int HD_  = H_ * DH_;   // 192
constexpr int CD_  = CB_ * DH_;  // 512
constexpr int nC_  = N_ / CB_;   // 32
constexpr int nF_  = N_ / SB_;   // 64
constexpr float SCALE_ = 0.17677669529663687f; // 32^-0.5
constexpr float NEG_ = -3.4e38f;

// ---------------------------------------------------------------------------
// K1: embed + RMS-ish norm + Q/K/V/gate projections + RoPE + pos-added copies
// 256 threads = 4 waves; each wave handles 8 consecutive n (32 rows/block)
// ---------------------------------------------------------------------------
__global__ __launch_bounds__(256) void k_embed(
    const float* __restrict__ x, const float* __restrict__ We, const float* __restrict__ be,
    const float* __restrict__ gamma,
    const float* __restrict__ Wq, const float* __restrict__ Wk, const float* __restrict__ Wv,
    const float* __restrict__ kpos, const float* __restrict__ vpos,
    const float* __restrict__ Wg, const float* __restrict__ bg,
    float* __restrict__ q, float* __restrict__ qr, float* __restrict__ kr,
    float* __restrict__ v, float* __restrict__ kin, float* __restrict__ vin,
    float* __restrict__ g)
{
    const int t  = threadIdx.x;
    const int wv = t >> 6;
    const int ln = t & 63;
    const int n00 = blockIdx.x * 32;
    const int b = n00 / N_;
    const int nbase = (n00 % N_) + wv * 8;

    __shared__ float hn[32][64];

    // phase 1: normalized embedding rows
    for (int r = 0; r < 8; ++r) {
        const int n = nbase + r;
        float xv = x[b * N_ + n];
        float h = fmaf(xv, We[ln], be[ln]);
        float ss = h * h;
        #pragma unroll
        for (int off = 32; off; off >>= 1) ss += __shfl_down(ss, off);
        ss = __shfl(ss, 0);
        float sc = 8.0f / fmaxf(sqrtf(ss), 1e-12f);
        hn[wv * 8 + r][ln] = h * sc * (gamma[ln] + 1.0f);
    }
    __syncthreads();

    // phase 2: projections (each lane owns output column e = ln + 64*m)
    #pragma unroll
    for (int m = 0; m < 3; ++m) {
        const int e  = ln + (m << 6);
        const int hh = e >> 5;
        const int dh = e & 31;
        float aq[8], ak[8], av[8];
        #pragma unroll
        for (int r = 0; r < 8; ++r) { aq[r] = 0.f; ak[r] = 0.f; av[r] = 0.f; }
        for (int dd = 0; dd < 64; ++dd) {
            const float wq_ = Wq[dd * HD_ + e];
            const float wk_ = Wk[dd * HD_ + e];
            const float wv_ = Wv[dd * HD_ + e];
            #pragma unroll
            for (int r = 0; r < 8; ++r) {
                const float hv = hn[wv * 8 + r][dd];
                aq[r] = fmaf(hv, wq_, aq[r]);
                ak[r] = fmaf(hv, wk_, ak[r]);
                av[r] = fmaf(hv, wv_, av[r]);
            }
        }
        const float invf = powf(10000.0f, -(float)(dh & ~1) * (1.0f / 32.0f));
        #pragma unroll
        for (int r = 0; r < 8; ++r) {
            const int n = nbase + r;
            const size_t o = ((size_t)(b * H_ + hh) * N_ + n) * DH_ + dh;
            q[o] = aq[r];
            v[o] = av[r];
            const int pix = (hh * CB_ + (n & (CB_ - 1))) * DH_ + dh;
            kin[o] = ak[r] + kpos[pix];
            vin[o] = av[r] + vpos[pix];
            // RoPE (interleaved pairs); partner lane = ln^1 (same r, e^1)
            const float aqp = __shfl_xor(aq[r], 1);
            const float akp = __shfl_xor(ak[r], 1);
            const float ang = (float)n * invf;
            const float cA = cosf(ang), sA = sinf(ang);
            float rq, rk;
            if (dh & 1) { rq = fmaf(aqp, sA, aq[r] * cA); rk = fmaf(akp, sA, ak[r] * cA); }
            else        { rq = fmaf(-aqp, sA, aq[r] * cA); rk = fmaf(-akp, sA, ak[r] * cA); }
            qr[o] = rq; kr[o] = rk;
        }
    }

    // gate: 18 outputs per row
    if (ln < 18) {
        #pragma unroll 2
        for (int r = 0; r < 8; ++r) {
            const int n = nbase + r;
            float a = bg[ln];
            for (int dd = 0; dd < 64; ++dd) a = fmaf(hn[wv * 8 + r][dd], Wg[dd * 18 + ln], a);
            const float gv = 1.0f / (1.0f + expf(-a));
            g[((size_t)(b * H_ + ln / 3) * N_ + n) * 3 + (ln % 3)] = gv;
        }
    }
}

// ---------------------------------------------------------------------------
// K1b: memory token -> slot 0 of ck/cv
// ---------------------------------------------------------------------------
__global__ void k_memtok(const float* __restrict__ mk, const float* __restrict__ mv,
                         float* __restrict__ ck, float* __restrict__ cv)
{
    const int bh = blockIdx.x;
    const int h = bh % H_;
    const int t = threadIdx.x; // 32
    ck[(size_t)bh * 33 * DH_ + t] = mk[h * DH_ + t];
    cv[(size_t)bh * 33 * DH_ + t] = mv[h * DH_ + t];
}

// ---------------------------------------------------------------------------
// K2: compression MLP (relu(in@W1+b1)@W2+b2), R=8 rows/block to amortize W1
// grid: (B*H*nC/8, 2)  y=0 -> k path, y=1 -> v path
// ---------------------------------------------------------------------------
__global__ __launch_bounds__(256) void k_compress(
    const float* __restrict__ kin, const float* __restrict__ vin,
    const float* __restrict__ Wk1, const float* __restrict__ bk1,
    const float* __restrict__ Wk2, const float* __restrict__ bk2,
    const float* __restrict__ Wv1, const float* __restrict__ bv1,
    const float* __restrict__ Wv2, const float* __restrict__ bv2,
    float* __restrict__ ck, float* __restrict__ cv)
{
    constexpr int R = 8;
    const bool isv = blockIdx.y != 0;
    const float* in = isv ? vin : kin;
    const float* W1 = isv ? Wv1 : Wk1;
    const float* b1 = isv ? bv1 : bk1;
    const float* W2 = isv ? Wv2 : Wk2;
    const float* b2 = isv ? bv2 : bk2;
    float* outp = isv ? cv : ck;

    const int row0 = blockIdx.x * R;   // row = (b*H+h)*nC + c
    const int t = threadIdx.x;

    __shared__ float xin[R][512];
    __shared__ float hid[R][512];

    #pragma unroll
    for (int r = 0; r < R; ++r) {
        xin[r][t]       = in[(size_t)(row0 + r) * 512 + t];
        xin[r][t + 256] = in[(size_t)(row0 + r) * 512 + t + 256];
    }
    __syncthreads();

    // layer 1: each thread computes 2 hidden units for all 8 rows
    #pragma unroll
    for (int jj = 0; jj < 2; ++jj) {
        const int j = t + jj * 256;
        float a[R];
        const float bb = b1[j];
        #pragma unroll
        for (int r = 0; r < R; ++r) a[r] = bb;
        for (int dd = 0; dd < 512; ++dd) {
            const float w = W1[(size_t)dd * 512 + j];
            #pragma unroll
            for (int r = 0; r < R; ++r) a[r] = fmaf(xin[r][dd], w, a[r]);
        }
        #pragma unroll
        for (int r = 0; r < R; ++r) hid[r][j] = fmaxf(a[r], 0.0f);
    }
    __syncthreads();

    // layer 2: 32 outputs; t = seg*32 + o, 8 segments of 64
    const int o = t & 31, seg = t >> 5;
    float s[R];
    #pragma unroll
    for (int r = 0; r < R; ++r) s[r] = 0.f;
    for (int dd = seg * 64; dd < seg * 64 + 64; ++dd) {
        const float w = W2[(size_t)dd * 32 + o];
        #pragma unroll
        for (int r = 0; r < R; ++r) s[r] = fmaf(hid[r][dd], w, s[r]);
    }
    __shared__ float red[R][256];
    #pragma unroll
    for (int r = 0; r < R; ++r) red[r][t] = s[r];
    __syncthreads();
    if (t < 128) {
        #pragma unroll
        for (int r = 0; r < R; ++r) red[r][t] += red[r][t + 128];
    }
    __syncthreads();
    if (t < 64) {
        #pragma unroll
        for (int r = 0; r < R; ++r) red[r][t] += red[r][t + 64];
    }
    __syncthreads();
    if (t < 32) {
        #pragma unroll
        for (int r = 0; r < R; ++r) {
            const float val = red[r][t] + red[r][t + 32] + b2[t];
            const int row = row0 + r;
            const int bh = row >> 5;   // / nC
            const int c  = row & 31;
            outp[((size_t)bh * 33 + 1 + c) * DH_ + t] = val;
        }
    }
}

// ---------------------------------------------------------------------------
// K3: compressed attention + importance top-2 selection. 1 thread per (b,h,n)
// ---------------------------------------------------------------------------
__global__ __launch_bounds__(256) void k_cattn(
    const float* __restrict__ q, const float* __restrict__ ck, const float* __restrict__ cv,
    float* __restrict__ cout, float* __restrict__ selv, int* __restrict__ seli, int BHN)
{
    const int tid = blockIdx.x * 256 + threadIdx.x;
    if (tid >= BHN) return;
    const int n = tid & (N_ - 1);
    const int bh = tid >> 9;

    float qv[32];
    #pragma unroll
    for (int d = 0; d < 32; ++d) qv[d] = q[(size_t)tid * 32 + d];
    const float* ckb = ck + (size_t)bh * 33 * DH_;
    const float* cvb = cv + (size_t)bh * 33 * DH_;

    float sim[33];
    float mx = -INFINITY;
    #pragma unroll
    for (int j = 0; j < 33; ++j) {
        const bool ok = (j == 0) || (j * CB_ - 1 < n);
        float a;
        if (ok) {
            a = 0.f;
            #pragma unroll
            for (int d = 0; d < 32; ++d) a = fmaf(qv[d], ckb[j * 32 + d], a);
            a *= SCALE_;
        } else a = NEG_;
        sim[j] = a;
        mx = fmaxf(mx, a);
    }
    float den = 0.f;
    float acc[32];
    #pragma unroll
    for (int d = 0; d < 32; ++d) acc[d] = 0.f;
    #pragma unroll
    for (int j = 0; j < 33; ++j) {
        const float p = expf(sim[j] - mx);
        den += p;
        #pragma unroll
        for (int d = 0; d < 32; ++d) acc[d] = fmaf(p, cvb[j * 32 + d], acc[d]);
    }
    const float invd = 1.0f / den;
    #pragma unroll
    for (int d = 0; d < 32; ++d) cout[(size_t)tid * 32 + d] = acc[d] * invd;

    // selection: imp[f] = sim[1 + f/2] if (n/SB > f) else NEG ; plus -1000 column
    const int qb = n >> 3;
    float m2 = -1000.0f;
    #pragma unroll
    for (int j = 1; j <= 32; ++j) {
        const int f0 = 2 * (j - 1);
        if (qb > f0) m2 = fmaxf(m2, sim[j]);   // covers f0+1 too (same value, weaker mask)
    }
    float sum2 = expf(-1000.0f - m2);
    float v1 = -INFINITY, v2 = -INFINITY;
    int i1 = 0, i2 = 0;
    #pragma unroll
    for (int j = 1; j <= 32; ++j) {
        const float sv = sim[j];
        #pragma unroll
        for (int u = 0; u < 2; ++u) {
            const int f = 2 * (j - 1) + u;
            const float iv = (qb > f) ? sv : NEG_;
            sum2 += expf(iv - m2);
            if (iv > v1)      { v2 = v1; i2 = i1; v1 = iv; i1 = f; }
            else if (iv > v2) { v2 = iv; i2 = f; }
        }
    }
    const float isum = 1.0f / sum2;
    selv[(size_t)tid * 2]     = expf(v1 - m2) * isum;
    selv[(size_t)tid * 2 + 1] = expf(v2 - m2) * isum;
    seli[(size_t)tid * 2]     = i1;
    seli[(size_t)tid * 2 + 1] = i2;
}

// ---------------------------------------------------------------------------
// K4: fine attention (2 selected + own block) + sliding window + gated combine
// 1 thread per (b,h,n); writes outbuf[b][n][h*DH+d]
// ---------------------------------------------------------------------------
__global__ __launch_bounds__(256) void k_fattn(
    const float* __restrict__ qr, const float* __restrict__ kr, const float* __restrict__ v,
    const float* __restrict__ cout, const float* __restrict__ g,
    const float* __restrict__ selv, const int* __restrict__ seli,
    float* __restrict__ outbuf, int BHN)
{
    const int tid = blockIdx.x * 256 + threadIdx.x;
    if (tid >= BHN) return;
    const int n = tid & (N_ - 1);
    const int bh = tid >> 9;
    const int b = bh / H_, h = bh % H_;

    float qv[32];
    #pragma unroll
    for (int d = 0; d < 32; ++d) qv[d] = qr[(size_t)tid * 32 + d];
    const float* krb = kr + (size_t)bh * N_ * DH_;
    const float* vb  = v  + (size_t)bh * N_ * DH_;

    const int qb = n >> 3;
    int blocks[3];
    blocks[0] = seli[(size_t)tid * 2];
    blocks[1] = seli[(size_t)tid * 2 + 1];
    blocks[2] = qb;
    bool bmask[2];
    bmask[0] = selv[(size_t)tid * 2]     > 1e-10f;
    bmask[1] = selv[(size_t)tid * 2 + 1] > 1e-10f;

    float sim[24];
    float mx = -INFINITY;
    #pragma unroll
    for (int s = 0; s < 3; ++s) {
        const int base = blocks[s] * SB_;
        #pragma unroll
        for (int j = 0; j < 8; ++j) {
            const bool ok = (s < 2) ? bmask[s] : (j <= (n & 7));
            float a;
            if (ok) {
                a = 0.f;
                #pragma unroll
                for (int d = 0; d < 32; ++d) a = fmaf(qv[d], krb[(size_t)(base + j) * 32 + d], a);
                a *= SCALE_;
            } else a = NEG_;
            sim[s * 8 + j] = a;
            mx = fmaxf(mx, a);
        }
    }
    float den = 0.f;
    float fo[32];
    #pragma unroll
    for (int d = 0; d < 32; ++d) fo[d] = 0.f;
    #pragma unroll
    for (int s = 0; s < 3; ++s) {
        const int base = blocks[s] * SB_;
        #pragma unroll
        for (int j = 0; j < 8; ++j) {
            const float p = expf(sim[s * 8 + j] - mx);
            den += p;
            #pragma unroll
            for (int d = 0; d < 32; ++d) fo[d] = fmaf(p, vb[(size_t)(base + j) * 32 + d], fo[d]);
        }
    }
    const float invd = 1.0f / den;

    // sliding window
    float sim2[8];
    float mx2 = -INFINITY;
    #pragma unroll
    for (int w = 0; w < 8; ++w) {
        float a;
        if (w <= n) {
            a = 0.f;
            #pragma unroll
            for (int d = 0; d < 32; ++d) a = fmaf(qv[d], krb[(size_t)(n - w) * 32 + d], a);
            a *= SCALE_;
        } else a = NEG_;
        sim2[w] = a;
        mx2 = fmaxf(mx2, a);
    }
    float den2 = 0.f;
    float so[32];
    #pragma unroll
    for (int d = 0; d < 32; ++d) so[d] = 0.f;
    #pragma unroll
    for (int w = 0; w < 8; ++w) {
        const float p = expf(sim2[w] - mx2);
        den2 += p;
        const int kc = (n - w) >= 0 ? (n - w) : 0;
        #pragma unroll
        for (int d = 0; d < 32; ++d) so[d] = fmaf(p, vb[(size_t)kc * 32 + d], so[d]);
    }
    const float invd2 = 1.0f / den2;

    const float g0 = g[(size_t)tid * 3];
    const float g1 = g[(size_t)tid * 3 + 1];
    const float g2 = g[(size_t)tid * 3 + 2];
    float* op = outbuf + ((size_t)(b * N_ + n) * HD_ + h * DH_);
    #pragma unroll
    for (int d = 0; d < 32; ++d) {
        op[d] = g0 * cout[(size_t)tid * 32 + d] + g1 * (fo[d] * invd) + g2 * (so[d] * invd2);
    }
}

// ---------------------------------------------------------------------------
// K5a: column sums over N of outbuf (B,N,192) -> (B,192)
// ---------------------------------------------------------------------------
__global__ void k_colsum(const float* __restrict__ outbuf, float* __restrict__ colsum)
{
    const int b = blockIdx.x;
    const int e = threadIdx.x; // 192
    float s = 0.f;
    for (int n = 0; n < N_; ++n) s += outbuf[((size_t)b * N_ + n) * HD_ + e];
    colsum[b * HD_ + e] = s;
}

// ---------------------------------------------------------------------------
// K5b: pooled = colsum@Wo/N ; gelu MLP head -> out (B,7)
// ---------------------------------------------------------------------------
__global__ void k_head(const float* __restrict__ colsum, const float* __restrict__ Wo,
                       const float* __restrict__ Wh1, const float* __restrict__ bh1,
                       const float* __restrict__ Wh2, const float* __restrict__ bh2,
                       float* __restrict__ out)
{
    const int b = blockIdx.x;
    const int t = threadIdx.x; // 64
    __shared__ float cs[192];
    __shared__ float pooled[64];
    __shared__ float hid[32];
    for (int i = t; i < 192; i += 64) cs[i] = colsum[b * HD_ + i];
    __syncthreads();
    float a = 0.f;
    for (int e = 0; e < 192; ++e) a = fmaf(cs[e], Wo[e * 64 + t], a);
    pooled[t] = a * (1.0f / (float)N_);
    __syncthreads();
    if (t < 32) {
        float s = bh1[t];
        for (int d = 0; d < 64; ++d) s = fmaf(pooled[d], Wh1[d * 32 + t], s);
        hid[t] = 0.5f * s * (1.0f + erff(s * 0.7071067811865476f)); // exact gelu
    }
    __syncthreads();
    if (t < 7) {
        float s = bh2[t];
        for (int j = 0; j < 32; ++j) s = fmaf(hid[j], Wh2[j * 7 + t], s);
        out[b * 7 + t] = s;
    }
}

// ---------------------------------------------------------------------------
extern "C" void kernel_launch(void* const* d_in, const int* in_sizes, int n_in,
                              void* d_out, int out_size, void* d_ws, size_t ws_size,
                              hipStream_t stream)
{
    const float* x     = (const float*)d_in[0];
    const float* We    = (const float*)d_in[1];
    const float* be    = (const float*)d_in[2];
    const float* gamma = (const float*)d_in[3];
    const float* Wq    = (const float*)d_in[4];
    const float* Wk    = (const float*)d_in[5];
    const float* Wv    = (const float*)d_in[6];
    const float* kpos  = (const float*)d_in[7];
    const float* vpos  = (const float*)d_in[8];
    const float* mk    = (const float*)d_in[9];
    const float* mv    = (const float*)d_in[10];
    const float* Wkc1  = (const float*)d_in[11];
    const float* bkc1  = (const float*)d_in[12];
    const float* Wkc2  = (const float*)d_in[13];
    const float* bkc2  = (const float*)d_in[14];
    const float* Wvc1  = (const float*)d_in[15];
    const float* bvc1  = (const float*)d_in[16];
    const float* Wvc2  = (const float*)d_in[17];
    const float* bvc2  = (const float*)d_in[18];
    const float* Wg    = (const float*)d_in[19];
    const float* bg    = (const float*)d_in[20];
    const float* Wo    = (const float*)d_in[21];
    const float* Wh1   = (const float*)d_in[22];
    const float* bh1   = (const float*)d_in[23];
    const float* Wh2   = (const float*)d_in[24];
    const float* bh2   = (const float*)d_in[25];
    float* out = (float*)d_out;

    const int B = in_sizes[0] / N_;
    const int BH = B * H_;
    const int BHN = BH * N_;
    const size_t SZ = (size_t)BHN * DH_;

    float* ws   = (float*)d_ws;
    float* q_   = ws;             // consumed by k_cattn; reused as outbuf by k_fattn
    float* qr_  = ws + SZ;
    float* kr_  = ws + 2 * SZ;
    float* v_   = ws + 3 * SZ;
    float* kin_ = ws + 4 * SZ;    // consumed by k_compress; reused as cout by k_cattn
    float* vin_ = ws + 5 * SZ;
    float* cout_ = kin_;
    float* outb_ = q_;
    float* ck_  = ws + 6 * SZ;
    float* cv_  = ck_ + (size_t)BH * 33 * DH_;
    float* g_   = cv_ + (size_t)BH * 33 * DH_;
    float* selv_ = g_ + (size_t)BHN * 3;
    int*   seli_ = (int*)(selv_ + (size_t)BHN * 2);
    float* csum_ = (float*)(seli_ + (size_t)BHN * 2);

    k_embed<<<dim3(B * N_ / 32), dim3(256), 0, stream>>>(
        x, We, be, gamma, Wq, Wk, Wv, kpos, vpos, Wg, bg,
        q_, qr_, kr_, v_, kin_, vin_, g_);
    k_memtok<<<dim3(BH), dim3(32), 0, stream>>>(mk, mv, ck_, cv_);
    k_compress<<<dim3(BH * nC_ / 8, 2), dim3(256), 0, stream>>>(
        kin_, vin_, Wkc1, bkc1, Wkc2, bkc2, Wvc1, bvc1, Wvc2, bvc2, ck_, cv_);
    k_cattn<<<dim3(BHN / 256), dim3(256), 0, stream>>>(
        q_, ck_, cv_, cout_, selv_, seli_, BHN);
    k_fattn<<<dim3(BHN / 256), dim3(256), 0, stream>>>(
        qr_, kr_, v_, cout_, g_, selv_, seli_, outb_, BHN);
    k_colsum<<<dim3(B), dim3(192), 0, stream>>>(outb_, csum_);
    k_head<<<dim3(B), dim3(64), 0, stream>>>(csum_, Wo, Wh1, bh1, Wh2, bh2, out);
}